// Round 11
// baseline (93.979 us; speedup 1.0000x reference)
//
#include <hip/hip_runtime.h>
#include <math.h>

// Problem constants (fixed by reference: H=256, N=64, CH=1, L=2048)
#define NH   256
#define NN   64
#define LSEQ 2048
#define RS   72       // u16 row stride for XT separated planes (144 B)
#define RSW  68       // u32 row stride for packed planes (272 B == 4 mod 32 banks)
#define PSZ  4608     // u16 elems per separated 64-row plane (64*72)
#define NTH  1024

typedef __attribute__((ext_vector_type(8))) short short8;     // 8 bf16 (MFMA A/B frag)
typedef __attribute__((ext_vector_type(4))) float float4_t;   // 16x16 MFMA C/D frag
typedef __attribute__((ext_vector_type(16))) float float16_t; // 32x32 MFMA C/D frag
typedef unsigned short u16;

#define MFMA(a,b,c)   __builtin_amdgcn_mfma_f32_16x16x32_bf16((a),(b),(c),0,0,0)
#define MFMA32(a,b,c) __builtin_amdgcn_mfma_f32_32x32x16_bf16((a),(b),(c),0,0,0)
#define PERM_HI 0x07060302u   // [a.hi16 | b.hi16]
#define PERM_LO 0x05040100u   // [a.lo16 | b.lo16]

// value v -> hi bits (bf16<<16) and lo bits (f32 of v-hi; top16 = lo bf16)
static __device__ __forceinline__ void split2(float v, unsigned& hb, unsigned& lb) {
    hb = __float_as_uint(v) & 0xffff0000u;
    lb = __float_as_uint(v - __uint_as_float(hb));
}
// packed word = [hi bf16 | lo bf16]
static __device__ __forceinline__ unsigned pack2(float v) {
    unsigned hb, lb; split2(v, hb, lb);
    return __builtin_amdgcn_perm(hb, lb, PERM_HI);
}
static __device__ __forceinline__ float unpack2(unsigned w) {
    return __uint_as_float(w & 0xffff0000u) + __uint_as_float(w << 16);
}
static __device__ __forceinline__ short8 neg8(short8 v) {
    union { short8 s; int i[4]; } u; u.s = v;
#pragma unroll
    for (int m = 0; m < 4; ++m) u.i[m] ^= 0x80008000;
    return u.s;
}

// hi/lo short8 frags from 8 packed words (2 uint4 loads + 8 v_perm)
static __device__ __forceinline__ void frag_packed(const unsigned* p, short8& hi, short8& lo) {
    const uint4* q = (const uint4*)p;
    uint4 d0 = q[0], d1 = q[1];
    unsigned e[8] = {d0.x, d0.y, d0.z, d0.w, d1.x, d1.y, d1.z, d1.w};
    union { short8 s; unsigned u[4]; } H, L;
#pragma unroll
    for (int m = 0; m < 4; ++m) {
        H.u[m] = __builtin_amdgcn_perm(e[2*m+1], e[2*m], PERM_HI);
        L.u[m] = __builtin_amdgcn_perm(e[2*m+1], e[2*m], PERM_LO);
    }
    hi = H.s; lo = L.s;
}

// hi/lo short8 frags from 8 f32 bit patterns (m1 global path only)
static __device__ __forceinline__ void frag_vals(const unsigned* e, short8& hi, short8& lo) {
    unsigned lb[8];
#pragma unroll
    for (int m = 0; m < 8; ++m) {
        unsigned hv = e[m] & 0xffff0000u;
        lb[m] = __float_as_uint(__uint_as_float(e[m]) - __uint_as_float(hv));
    }
    union { short8 s; unsigned u[4]; } H, L;
#pragma unroll
    for (int m = 0; m < 4; ++m) {
        H.u[m] = __builtin_amdgcn_perm(e[2*m+1],  e[2*m],  PERM_HI);
        L.u[m] = __builtin_amdgcn_perm(lb[2*m+1], lb[2*m], PERM_HI);
    }
    hi = H.s; lo = L.s;
}

// ---- cmm variants (all packed arrays are [hi|lo] u32, stride RSW) ----

// A packed x B packed, 16x16 (m2/m3 single-tile, X-riders s2-6, tail-K)
template<bool IMAG>
static __device__ __forceinline__ void cmm_pp(
    const unsigned* __restrict__ Aprl, const unsigned* __restrict__ ApiI,
    const unsigned* __restrict__ Bprl, const unsigned* __restrict__ BpiI,
    int arow, int bcol, int fq,
    float4_t& accP, float4_t& accN, float4_t& accI1, float4_t& accI2)
{
#pragma unroll
    for (int ks = 0; ks < 2; ++ks) {
        const int k0 = ks*32 + fq*8;
        short8 Arh, Arl, Aih, Ail, Brh, Brl, Bih, Bil;
        frag_packed(Aprl + arow*RSW + k0, Arh, Arl);
        frag_packed(ApiI + arow*RSW + k0, Aih, Ail);
        frag_packed(Bprl + bcol*RSW + k0, Brh, Brl);
        frag_packed(BpiI + bcol*RSW + k0, Bih, Bil);
        accP = MFMA(Arh, Brh, accP); accP = MFMA(Arh, Brl, accP); accP = MFMA(Arl, Brh, accP);
        accN = MFMA(Aih, Bih, accN); accN = MFMA(Aih, Bil, accN); accN = MFMA(Ail, Bih, accN);
        if (IMAG) {
            accI1 = MFMA(Arh, Bih, accI1); accI1 = MFMA(Arh, Bil, accI1); accI1 = MFMA(Arl, Bih, accI1);
            accI2 = MFMA(Aih, Brh, accI2); accI2 = MFMA(Aih, Brl, accI2); accI2 = MFMA(Ail, Brh, accI2);
        }
    }
}

// A packed x B separated (XT), 16x16 (G-riders s7-9, tail G-step)
template<int BSZ, bool IMAG>
static __device__ __forceinline__ void cmm_ps(
    const unsigned* __restrict__ Aprl, const unsigned* __restrict__ ApiI,
    const u16* __restrict__ Bb,
    int arow, int bcol, int fq,
    float4_t& accP, float4_t& accN, float4_t& accI1, float4_t& accI2)
{
#pragma unroll
    for (int ks = 0; ks < 2; ++ks) {
        const int k0 = ks*32 + fq*8;
        short8 Arh, Arl, Aih, Ail;
        frag_packed(Aprl + arow*RSW + k0, Arh, Arl);
        frag_packed(ApiI + arow*RSW + k0, Aih, Ail);
        const u16* bp = Bb + bcol*RS + k0;
        short8 Brh = *(const short8*)(bp);
        short8 Brl = *(const short8*)(bp + BSZ);
        short8 Bih = *(const short8*)(bp + 2*BSZ);
        short8 Bil = *(const short8*)(bp + 3*BSZ);
        accP = MFMA(Arh, Brh, accP); accP = MFMA(Arh, Brl, accP); accP = MFMA(Arl, Brh, accP);
        accN = MFMA(Aih, Bih, accN); accN = MFMA(Aih, Bil, accN); accN = MFMA(Ail, Bih, accN);
        if (IMAG) {
            accI1 = MFMA(Arh, Bih, accI1); accI1 = MFMA(Arh, Bil, accI1); accI1 = MFMA(Arl, Bih, accI1);
            accI2 = MFMA(Aih, Brh, accI2); accI2 = MFMA(Aih, Brl, accI2); accI2 = MFMA(Ail, Brh, accI2);
        }
    }
}

// 32x32, A packed (XR) x B separated (XT), 2-chain — ladder squaring
template<int BSZ>
static __device__ __forceinline__ void cmm32_pk(
    const unsigned* __restrict__ Aprl, const unsigned* __restrict__ ApiI,
    const u16* __restrict__ Bb,
    int arow, int bcol, int khalf,
    float16_t& R, float16_t& I)
{
#pragma unroll
    for (int ks = 0; ks < 4; ++ks) {
        const int k0 = ks*16 + khalf;
        short8 Arh, Arl, Aih, Ail;
        frag_packed(Aprl + arow*RSW + k0, Arh, Arl);
        frag_packed(ApiI + arow*RSW + k0, Aih, Ail);
        const u16* bp = Bb + bcol*RS + k0;
        short8 Brh = *(const short8*)(bp);
        short8 Brl = *(const short8*)(bp + BSZ);
        short8 Bih = *(const short8*)(bp + 2*BSZ);
        short8 Bil = *(const short8*)(bp + 3*BSZ);
        short8 nAih = neg8(Aih), nAil = neg8(Ail);
        R = MFMA32(Arh, Brh, R);  I = MFMA32(Arh, Bih, I);
        R = MFMA32(Arh, Brl, R);  I = MFMA32(Arh, Bil, I);
        R = MFMA32(Arl, Brh, R);  I = MFMA32(Arl, Bih, I);
        R = MFMA32(nAih, Bih, R); I = MFMA32(Aih, Brh, I);
        R = MFMA32(nAih, Bil, R); I = MFMA32(Aih, Brl, I);
        R = MFMA32(nAil, Bih, R); I = MFMA32(Ail, Brh, I);
    }
}

// XT (transposed, separated planes) b64 store of 4 consecutive rows at one col
static __device__ __forceinline__ void store_XT16(
    u16* XT, int rowbase, int bcol, const float* p_r, const float* p_i)
{
    unsigned hR[4], lR[4], hI[4], lI[4];
#pragma unroll
    for (int r = 0; r < 4; ++r) { split2(p_r[r], hR[r], lR[r]); split2(p_i[r], hI[r], lI[r]); }
    int tb = bcol*RS + rowbase;
    uint2 w;
    w.x = __builtin_amdgcn_perm(hR[1], hR[0], PERM_HI);
    w.y = __builtin_amdgcn_perm(hR[3], hR[2], PERM_HI);
    *(uint2*)&XT[tb] = w;
    w.x = __builtin_amdgcn_perm(lR[1], lR[0], PERM_HI);
    w.y = __builtin_amdgcn_perm(lR[3], lR[2], PERM_HI);
    *(uint2*)&XT[PSZ + tb] = w;
    w.x = __builtin_amdgcn_perm(hI[1], hI[0], PERM_HI);
    w.y = __builtin_amdgcn_perm(hI[3], hI[2], PERM_HI);
    *(uint2*)&XT[2*PSZ + tb] = w;
    w.x = __builtin_amdgcn_perm(lI[1], lI[0], PERM_HI);
    w.y = __builtin_amdgcn_perm(lI[3], lI[2], PERM_HI);
    *(uint2*)&XT[3*PSZ + tb] = w;
}

// k[h, 64j+i] = Re( g_j . x_i ),  g_j = c^T (dA^64)^j,  x_i = dA^i dB
// Cubic Newton: X1 = I + (dt/2)A; Y = Ab*X1; V = X1*Y; X2 = 3X1 - 3V + VY.
// P = dA = 2*X2 - I folded into m3 epilogue.
// dB = dt/2 (dA b + b): u = dA*b, then x0 = dt/2(u+b), x1 = dt/2(dA u + u).
// m1/m2/m3 on ALL 16 waves (single 16x16 tiles, 4x4 grid — round-10
// post-mortem: latency-bound, 8-wave pairing left half the CU idle).
// Ladder: 9 squarings to dA^512 on waves 0-3 (32x32, 2-chain, setprio);
// riders concurrent on waves 8-15. XR/XF/Gm pair-packed u32; XT separated
// planes and DOUBLE-BUFFERED (XT stores pre-barrier into the other buffer).
// Parity: m3 writes XT0; round s reads XT[(s-1)&1], writes XT[s&1]; tail XT1.
__global__ __launch_bounds__(NTH, 4) void ssm_kernel(
    const float* __restrict__ Ag,
    const float* __restrict__ Bg,
    const float* __restrict__ Cg,
    const float* __restrict__ LogDt,
    float* __restrict__ outp)
{
    __shared__ __align__(16) unsigned char lds[161792];
    unsigned* XRrl = (unsigned*)(lds);           // packed P rows [rh|rl] (17408 B)
    unsigned* XRiI = (unsigned*)(lds + 17408);   // packed P rows [ih|il]
    u16*      XT0  = (u16*)(lds +  34816);       // P^T separated, buffer 0 (36864 B)
    u16*      XT1  = (u16*)(lds +  71680);       // P^T separated, buffer 1 (36864 B)
    unsigned* XFrl = (unsigned*)(lds + 108544);  // packed Xf rows (Y^T in Newton)
    unsigned* XFiI = (unsigned*)(lds + 125952);
    unsigned* Gmrl = (unsigned*)(lds + 143360);  // packed G rows (32 x RSW)
    unsigned* GmiI = (unsigned*)(lds + 152064);
    float* bvr = (float*)(lds + 160768);
    float* bvi = (float*)(lds + 161024);
    float* urr = (float*)(lds + 161280);   // u = dA*b scratch
    float* uri = (float*)(lds + 161536);

    const int t    = threadIdx.x;
    const int lane = t & 63;
    const int wv   = t >> 6;                 // 0..15
    const int fm   = lane & 15, fq = lane >> 4;
    const int h    = blockIdx.x;

    // m-round single-tile mapping (all 16 waves): 4x4 tile grid
    const int tim  = wv >> 2, tjm = wv & 3;
    const int marow = tim*16 + fm;
    const int mbcol = tjm*16 + fm;

    // 32x32 squaring mapping (waves 0-3): tile (ti2, tj2)
    const int ti2 = (wv >> 1) & 1, tj2 = wv & 1;
    const int arow32 = ti2*32 + (lane & 31);
    const int bcol32 = tj2*32 + (lane & 31);
    const int khalf  = (lane >> 5) * 8;

    const float dt  = expf(LogDt[h]);
    const float hdt = 0.5f * dt;

    const float2* A2 = (const float2*)(Ag + (size_t)h * NN * NN * 2);
    const float4_t z4 = {0.f, 0.f, 0.f, 0.f};

    // ---- seed P = X1 = I + (dt/2)A (XR packed + XT0); load b, c ----
#pragma unroll
    for (int e = 0; e < 4; ++e) {
        int idx = t + e*NTH;
        int i = idx >> 6, j = idx & 63;
        float2 a = A2[idx];
        float x1r = (i == j ? 1.0f : 0.0f) + hdt * a.x;
        float x1i = hdt * a.y;
        XRrl[i*RSW + j] = pack2(x1r);
        XRiI[i*RSW + j] = pack2(x1i);
        unsigned hb, lb;
        split2(x1r, hb, lb);
        XT0[j*RS + i]       = (u16)(hb >> 16);
        XT0[PSZ + j*RS + i] = (u16)(lb >> 16);
        split2(x1i, hb, lb);
        XT0[2*PSZ + j*RS + i] = (u16)(hb >> 16);
        XT0[3*PSZ + j*RS + i] = (u16)(lb >> 16);
    }
    if (t < NN) {
        float2 bv = ((const float2*)Bg)[h*NN + t];
        float2 cv = ((const float2*)Cg)[h*NN + t];
        bvr[t] = bv.x; bvi[t] = bv.y;
        Gmrl[t] = pack2(cv.x);                // g_0 = c (row 0)
        GmiI[t] = pack2(cv.y);
    }
    __syncthreads();

    // ---- m1: Y = Ab*X1 (Ab from global, Bt = XT0); 16 waves; Y^T -> XF ----
    {
        float4_t aP = z4, aN = z4, aI1 = z4, aI2 = z4;
#pragma unroll
        for (int ks = 0; ks < 2; ++ks) {
            const int k0 = ks*32 + fq*8;
            unsigned vr[8], vi[8];
#pragma unroll
            for (int j = 0; j < 8; ++j) {
                float2 a = A2[marow*NN + k0 + j];
                vr[j] = __float_as_uint((marow == k0 + j ? 1.0f : 0.0f) - hdt * a.x);
                vi[j] = __float_as_uint(-hdt * a.y);
            }
            short8 Arh, Arl, Aih, Ail;
            frag_vals(vr, Arh, Arl);
            frag_vals(vi, Aih, Ail);
            const u16* bp = XT0 + mbcol*RS + k0;
            short8 Brh = *(const short8*)(bp);
            short8 Brl = *(const short8*)(bp + PSZ);
            short8 Bih = *(const short8*)(bp + 2*PSZ);
            short8 Bil = *(const short8*)(bp + 3*PSZ);
            aP = MFMA(Arh, Brh, aP); aP = MFMA(Arh, Brl, aP); aP = MFMA(Arl, Brh, aP);
            aN = MFMA(Aih, Bih, aN); aN = MFMA(Aih, Bil, aN); aN = MFMA(Ail, Bih, aN);
            aI1 = MFMA(Arh, Bih, aI1); aI1 = MFMA(Arh, Bil, aI1); aI1 = MFMA(Arl, Bih, aI1);
            aI2 = MFMA(Aih, Brh, aI2); aI2 = MFMA(Aih, Brl, aI2); aI2 = MFMA(Ail, Brh, aI2);
        }
#pragma unroll
        for (int rp = 0; rp < 2; ++rp) {   // Y^T contiguous rows -> packed uint2
            int row0 = tim*16 + fq*4 + rp*2;
            uint2 w;
            w.x = pack2(aP[rp*2]   - aN[rp*2]);
            w.y = pack2(aP[rp*2+1] - aN[rp*2+1]);
            *(uint2*)&XFrl[mbcol*RSW + row0] = w;
            w.x = pack2(aI1[rp*2]   + aI2[rp*2]);
            w.y = pack2(aI1[rp*2+1] + aI2[rp*2+1]);
            *(uint2*)&XFiI[mbcol*RSW + row0] = w;
        }
    }
    __syncthreads();

    // ---- m2: V = X1*Y (A = XR packed, Bt = U = XF packed); 16 waves ----
    {
        float4_t aP = z4, aN = z4, aI1 = z4, aI2 = z4;
        cmm_pp<true>(XRrl, XRiI, XFrl, XFiI, marow, mbcol, fq, aP, aN, aI1, aI2);
        __syncthreads();   // all X1/Y reads done
#pragma unroll
        for (int r = 0; r < 4; ++r) {
            int row = tim*16 + fq*4 + r;
            XRrl[row*RSW + mbcol] = pack2(aP[r] - aN[r]);
            XRiI[row*RSW + mbcol] = pack2(aI1[r] + aI2[r]);
        }
    }
    __syncthreads();

    // ---- m3: P = dA = 2*(3X1 - 3V + V*Y) - I ; 16 waves; XT0 pre-barrier ----
    {
        float p_r[4], p_i[4];
        {
            float4_t aP = z4, aN = z4, aI1 = z4, aI2 = z4;
            cmm_pp<true>(XRrl, XRiI, XFrl, XFiI, marow, mbcol, fq, aP, aN, aI1, aI2);
#pragma unroll
            for (int r = 0; r < 4; ++r) {      // pre-barrier elementwise reads
                int row = tim*16 + fq*4 + r;
                float2 a = A2[row*NN + mbcol];
                float dd  = (row == mbcol ? 1.0f : 0.0f);
                float x1r = dd + hdt * a.x;
                float x1i = hdt * a.y;
                float vvr = unpack2(XRrl[row*RSW + mbcol]);
                float vvi = unpack2(XRiI[row*RSW + mbcol]);
                p_r[r] = 2.0f*(3.0f*x1r - 3.0f*vvr + (aP[r] - aN[r])) - dd;
                p_i[r] = 2.0f*(3.0f*x1i - 3.0f*vvi + (aI1[r] + aI2[r]));
            }
            // XT0 has no reader during m3 -> store pre-barrier
            store_XT16(XT0, tim*16 + fq*4, mbcol, p_r, p_i);
        }
        __syncthreads();   // all V/Y reads done
#pragma unroll
        for (int r = 0; r < 4; ++r) {
            int row = tim*16 + fq*4 + r;
            XRrl[row*RSW + mbcol] = pack2(p_r[r]);
            XRiI[row*RSW + mbcol] = pack2(p_i[r]);
        }
    }
    __syncthreads();
    // P = dA (XR packed + XT0)

    // ---- u = dA*b (all 16 waves; lane owns 4 consecutive k -> uint4 reads) ----
    {
        int n = t >> 4, part = t & 15;
        uint4 Wr = *(const uint4*)(XRrl + n*RSW + part*4);
        uint4 Wi = *(const uint4*)(XRiI + n*RSW + part*4);
        unsigned wr[4] = {Wr.x, Wr.y, Wr.z, Wr.w};
        unsigned wi[4] = {Wi.x, Wi.y, Wi.z, Wi.w};
        float ar = 0.f, ai = 0.f;
#pragma unroll
        for (int e = 0; e < 4; ++e) {
            float mr = unpack2(wr[e]);
            float mi = unpack2(wi[e]);
            int k = part*4 + e;
            ar += mr*bvr[k] - mi*bvi[k];
            ai += mr*bvi[k] + mi*bvr[k];
        }
#pragma unroll
        for (int off = 8; off; off >>= 1) { ar += __shfl_xor(ar, off); ai += __shfl_xor(ai, off); }
        if (part == 0) { urr[n] = ar; uri[n] = ai; }
    }
    __syncthreads();

    // ---- ladder s = 1..9: riders (waves 8-15) CONCURRENT with 32x32 squaring (waves 0-3) ----
#pragma unroll 1
    for (int s = 1; s <= 9; ++s) {
        u16* XTcur = (s & 1) ? XT0 : XT1;   // written by previous round (m3 for s=1)
        u16* XTnx  = (s & 1) ? XT1 : XT0;   // no reader this round
        float16_t sR, sI;
        if (wv >= 8) {
            if (s == 1) {
                // x0 = h(u+b); x1 = h(dA u + u): 512 threads; lane owns 8 consecutive k
                int n = (t >> 3) & 63, part = t & 7;
                const unsigned* rp0 = XRrl + n*RSW + part*8;
                const unsigned* ip0 = XRiI + n*RSW + part*8;
                uint4 Wr0 = *(const uint4*)(rp0), Wr1 = *(const uint4*)(rp0 + 4);
                uint4 Wi0 = *(const uint4*)(ip0), Wi1 = *(const uint4*)(ip0 + 4);
                unsigned wr[8] = {Wr0.x, Wr0.y, Wr0.z, Wr0.w, Wr1.x, Wr1.y, Wr1.z, Wr1.w};
                unsigned wi[8] = {Wi0.x, Wi0.y, Wi0.z, Wi0.w, Wi1.x, Wi1.y, Wi1.z, Wi1.w};
                float ar = 0.f, ai = 0.f;
#pragma unroll
                for (int e = 0; e < 8; ++e) {
                    float mr = unpack2(wr[e]);
                    float mi = unpack2(wi[e]);
                    int k = part*8 + e;
                    ar += mr*urr[k] - mi*uri[k];
                    ai += mr*uri[k] + mi*urr[k];
                }
#pragma unroll
                for (int off = 4; off; off >>= 1) { ar += __shfl_xor(ar, off); ai += __shfl_xor(ai, off); }
                if (part == 0) {
                    float u_r = urr[n], u_i = uri[n];
                    XFrl[n]       = pack2(hdt*(u_r + bvr[n]));
                    XFiI[n]       = pack2(hdt*(u_i + bvi[n]));
                    XFrl[RSW + n] = pack2(hdt*(ar + u_r));
                    XFiI[RSW + n] = pack2(hdt*(ai + u_i));
                }
            } else if (s <= 6) {
                const int C = 1 << (s-1);
                const int w = wv - 8;
                const int nT = (s == 6) ? 8 : 4;
                if (w < nT) {
                    const int rt = w >> 2, ct = w & 3;
                    float4_t aP = z4, aN = z4, aI1 = z4, aI2 = z4;
                    cmm_pp<true>(XFrl, XFiI, XRrl, XRiI, rt*16 + fm, ct*16 + fm, fq, aP, aN, aI1, aI2);
#pragma unroll
                    for (int r = 0; r < 4; ++r) {
                        int orow = C + rt*16 + fq*4 + r;
                        int oc   = ct*16 + fm;
                        XFrl[orow*RSW + oc] = pack2(aP[r] - aN[r]);
                        XFiI[orow*RSW + oc] = pack2(aI1[r] + aI2[r]);
                    }
                }
            } else {
                const int C = 1 << (s-7);     // 1,2,4
                const int w = wv - 8;
                if (w < 4) {
                    float4_t aP = z4, aN = z4, aI1 = z4, aI2 = z4;
                    cmm_ps<PSZ, true>(Gmrl, GmiI, XTcur, fm, w*16 + fm, fq, aP, aN, aI1, aI2);
#pragma unroll
                    for (int r = 0; r < 4; ++r) {
                        int orow = C + fq*4 + r;   // <= 19 < 32, no mask
                        int oc   = w*16 + fm;
                        Gmrl[orow*RSW + oc] = pack2(aP[r] - aN[r]);
                        GmiI[orow*RSW + oc] = pack2(aI1[r] + aI2[r]);
                    }
                }
            }
        } else if (wv < 4) {
            // squaring (waves 0-3, 32x32 tiles, 2-chain): P <- P*P
#pragma unroll
            for (int g = 0; g < 16; ++g) { sR[g] = 0.f; sI[g] = 0.f; }
            __builtin_amdgcn_s_setprio(1);   // T5: favor the long-pole MFMA waves
            cmm32_pk<PSZ>(XRrl, XRiI, XTcur, arow32, bcol32, khalf, sR, sI);
            __builtin_amdgcn_s_setprio(0);
            // pre-barrier: XT_next stores (no reader this round), overlapped
            // with rider compute still in flight
            {
                const int col = tj2*32 + (lane & 31);
                const int hi4 = (lane >> 5) * 4;
#pragma unroll
                for (int q = 0; q < 4; ++q) {
                    float r4[4], i4[4];
#pragma unroll
                    for (int rr = 0; rr < 4; ++rr) { r4[rr] = sR[4*q+rr]; i4[rr] = sI[4*q+rr]; }
                    store_XT16(XTnx, ti2*32 + 8*q + hi4, col, r4, i4);
                }
            }
        }
        __syncthreads();   // all XR reads (riders + frags) complete
        if (wv < 4 && s < 9) {
            // XR b32 packed stores (dead at s=9 -> skipped)
            const int col = tj2*32 + (lane & 31);
            const int hi4 = (lane >> 5) * 4;
#pragma unroll
            for (int q = 0; q < 4; ++q) {
                const int rowb = ti2*32 + 8*q + hi4;
#pragma unroll
                for (int rr = 0; rr < 4; ++rr) {
                    XRrl[(rowb + rr)*RSW + col] = pack2(sR[4*q+rr]);
                    XRiI[(rowb + rr)*RSW + col] = pack2(sI[4*q+rr]);
                }
            }
        }
        __syncthreads();
    }
    // P = dA^512 (XT1) ; XF rows 0..63 = x_i ; Gm rows 0..7 = g_0..g_7

    // ---- tail tt = 0..3: chained dA^512 G-steps + K tiles (direct global) ----
    // G rows [8+8tt, 24+8tt) <- A rows [8tt, 8tt+16) (out row 8+ab+m depends
    // only on A row ab+m, so in-interval row overlap is benign).
#pragma unroll 1
    for (int tt = 0; tt < 4; ++tt) {
        if (tt < 3 && wv < 4) {
            const int ab = tt * 8;
            float4_t aP = z4, aN = z4, aI1 = z4, aI2 = z4;
            cmm_ps<PSZ, true>(Gmrl, GmiI, XT1, ab + fm, wv*16 + fm, fq, aP, aN, aI1, aI2);
#pragma unroll
            for (int r = 0; r < 4; ++r) {
                int orow = 8 + ab + fq*4 + r;
                if (orow < 32) {
                    int oc = wv*16 + fm;
                    Gmrl[orow*RSW + oc] = pack2(aP[r] - aN[r]);
                    GmiI[orow*RSW + oc] = pack2(aI1[r] + aI2[r]);
                }
            }
        }
        if (wv >= 4 && wv < 8) {           // K rows [8tt, 8tt+8): direct global store
            const int jb = tt * 8;
            // clamp A row inside Gm's 32 rows (rows >= 32 feed only discarded C rows)
            int ga = jb + fm; if (ga > 31) ga = 31;
            float4_t aP = z4, aN = z4, aI1 = z4, aI2 = z4;
            __builtin_amdgcn_s_setprio(1);
            cmm_pp<false>(Gmrl, GmiI, XFrl, XFiI, ga, (wv-4)*16 + fm, fq, aP, aN, aI1, aI2);
            __builtin_amdgcn_s_setprio(0);
            if (fq < 2) {
                size_t base = (size_t)h * LSEQ;
#pragma unroll
                for (int r = 0; r < 4; ++r)
                    outp[base + (jb + fq*4 + r)*NN + (wv-4)*16 + fm] = aP[r] - aN[r];
            }
        }
        if (tt < 3) __syncthreads();
    }
}

extern "C" void kernel_launch(void* const* d_in, const int* in_sizes, int n_in,
                              void* d_out, int out_size, void* d_ws, size_t ws_size,
                              hipStream_t stream) {
    const float* A  = (const float*)d_in[0];
    const float* B  = (const float*)d_in[1];
    const float* C  = (const float*)d_in[2];
    const float* ld = (const float*)d_in[3];
    float* out = (float*)d_out;
    ssm_kernel<<<dim3(NH), dim3(NTH), 0, stream>>>(A, B, C, ld, out);
}

// Round 12
// 91.856 us; speedup vs baseline: 1.0231x; 1.0231x over previous
//
#include <hip/hip_runtime.h>
#include <math.h>

// Problem constants (fixed by reference: H=256, N=64, CH=1, L=2048)
#define NH   256
#define NN   64
#define LSEQ 2048
#define RSW  68       // u32 row stride for ALL packed planes (272 B == 4 mod 32 banks)
#define NTH  1024

typedef __attribute__((ext_vector_type(8))) short short8;     // 8 bf16 (MFMA A/B frag)
typedef __attribute__((ext_vector_type(4))) float float4_t;   // 16x16 MFMA C/D frag
typedef __attribute__((ext_vector_type(16))) float float16_t; // 32x32 MFMA C/D frag
typedef unsigned short u16;

#define MFMA(a,b,c)   __builtin_amdgcn_mfma_f32_16x16x32_bf16((a),(b),(c),0,0,0)
#define MFMA32(a,b,c) __builtin_amdgcn_mfma_f32_32x32x16_bf16((a),(b),(c),0,0,0)
#define PERM_HI 0x07060302u   // [a.hi16 | b.hi16]
#define PERM_LO 0x05040100u   // [a.lo16 | b.lo16]

// value v -> hi bits (bf16<<16) and lo bits (f32 of v-hi; top16 = lo bf16)
static __device__ __forceinline__ void split2(float v, unsigned& hb, unsigned& lb) {
    hb = __float_as_uint(v) & 0xffff0000u;
    lb = __float_as_uint(v - __uint_as_float(hb));
}
// packed word = [hi bf16 | lo bf16]
static __device__ __forceinline__ unsigned pack2(float v) {
    unsigned hb, lb; split2(v, hb, lb);
    return __builtin_amdgcn_perm(hb, lb, PERM_HI);
}
static __device__ __forceinline__ float unpack2(unsigned w) {
    return __uint_as_float(w & 0xffff0000u) + __uint_as_float(w << 16);
}
static __device__ __forceinline__ short8 neg8(short8 v) {
    union { short8 s; int i[4]; } u; u.s = v;
#pragma unroll
    for (int m = 0; m < 4; ++m) u.i[m] ^= 0x80008000;
    return u.s;
}

// hi/lo short8 frags from 8 packed words (2 uint4 loads + 8 v_perm)
static __device__ __forceinline__ void frag_packed(const unsigned* p, short8& hi, short8& lo) {
    const uint4* q = (const uint4*)p;
    uint4 d0 = q[0], d1 = q[1];
    unsigned e[8] = {d0.x, d0.y, d0.z, d0.w, d1.x, d1.y, d1.z, d1.w};
    union { short8 s; unsigned u[4]; } H, L;
#pragma unroll
    for (int m = 0; m < 4; ++m) {
        H.u[m] = __builtin_amdgcn_perm(e[2*m+1], e[2*m], PERM_HI);
        L.u[m] = __builtin_amdgcn_perm(e[2*m+1], e[2*m], PERM_LO);
    }
    hi = H.s; lo = L.s;
}

// hi/lo short8 frags from 8 f32 bit patterns (m1 global path only)
static __device__ __forceinline__ void frag_vals(const unsigned* e, short8& hi, short8& lo) {
    unsigned lb[8];
#pragma unroll
    for (int m = 0; m < 8; ++m) {
        unsigned hv = e[m] & 0xffff0000u;
        lb[m] = __float_as_uint(__uint_as_float(e[m]) - __uint_as_float(hv));
    }
    union { short8 s; unsigned u[4]; } H, L;
#pragma unroll
    for (int m = 0; m < 4; ++m) {
        H.u[m] = __builtin_amdgcn_perm(e[2*m+1],  e[2*m],  PERM_HI);
        L.u[m] = __builtin_amdgcn_perm(lb[2*m+1], lb[2*m], PERM_HI);
    }
    hi = H.s; lo = L.s;
}

// ---- cmm variants (ALL arrays pair-packed [hi|lo] u32, stride RSW) ----

// A packed x B packed, 16x16 (X-riders s2-6, G-riders s7-9, tail)
template<bool IMAG>
static __device__ __forceinline__ void cmm_pp(
    const unsigned* __restrict__ Aprl, const unsigned* __restrict__ ApiI,
    const unsigned* __restrict__ Bprl, const unsigned* __restrict__ BpiI,
    int arow, int bcol, int fq,
    float4_t& accP, float4_t& accN, float4_t& accI1, float4_t& accI2)
{
#pragma unroll
    for (int ks = 0; ks < 2; ++ks) {
        const int k0 = ks*32 + fq*8;
        short8 Arh, Arl, Aih, Ail, Brh, Brl, Bih, Bil;
        frag_packed(Aprl + arow*RSW + k0, Arh, Arl);
        frag_packed(ApiI + arow*RSW + k0, Aih, Ail);
        frag_packed(Bprl + bcol*RSW + k0, Brh, Brl);
        frag_packed(BpiI + bcol*RSW + k0, Bih, Bil);
        accP = MFMA(Arh, Brh, accP); accP = MFMA(Arh, Brl, accP); accP = MFMA(Arl, Brh, accP);
        accN = MFMA(Aih, Bih, accN); accN = MFMA(Aih, Bil, accN); accN = MFMA(Ail, Bih, accN);
        if (IMAG) {
            accI1 = MFMA(Arh, Bih, accI1); accI1 = MFMA(Arh, Bil, accI1); accI1 = MFMA(Arl, Bih, accI1);
            accI2 = MFMA(Aih, Brh, accI2); accI2 = MFMA(Aih, Brl, accI2); accI2 = MFMA(Ail, Brh, accI2);
        }
    }
}

// A packed x B packed, paired B-cols (m2/m3; A-frags loaded once for 2 tiles)
static __device__ __forceinline__ void cmm_pair_pp(
    const unsigned* __restrict__ Aprl, const unsigned* __restrict__ ApiI,
    const unsigned* __restrict__ Bprl, const unsigned* __restrict__ BpiI,
    int arow, int bcol0, int fq,
    float4_t& P0, float4_t& N0, float4_t& I10, float4_t& I20,
    float4_t& P1, float4_t& N1, float4_t& I11, float4_t& I21)
{
#pragma unroll
    for (int ks = 0; ks < 2; ++ks) {
        const int k0 = ks*32 + fq*8;
        short8 Arh, Arl, Aih, Ail;
        frag_packed(Aprl + arow*RSW + k0, Arh, Arl);
        frag_packed(ApiI + arow*RSW + k0, Aih, Ail);
#pragma unroll
        for (int p = 0; p < 2; ++p) {
            short8 Brh, Brl, Bih, Bil;
            frag_packed(Bprl + (bcol0 + p*16)*RSW + k0, Brh, Brl);
            frag_packed(BpiI + (bcol0 + p*16)*RSW + k0, Bih, Bil);
            float4_t &aP = p ? P1 : P0, &aN = p ? N1 : N0;
            float4_t &aI1 = p ? I11 : I10, &aI2 = p ? I21 : I20;
            aP = MFMA(Arh, Brh, aP); aP = MFMA(Arh, Brl, aP); aP = MFMA(Arl, Brh, aP);
            aN = MFMA(Aih, Bih, aN); aN = MFMA(Aih, Bil, aN); aN = MFMA(Ail, Bih, aN);
            aI1 = MFMA(Arh, Bih, aI1); aI1 = MFMA(Arh, Bil, aI1); aI1 = MFMA(Arl, Bih, aI1);
            aI2 = MFMA(Aih, Brh, aI2); aI2 = MFMA(Aih, Brl, aI2); aI2 = MFMA(Ail, Brh, aI2);
        }
    }
}

// 32x32, A packed (XR) x B packed (XT), 2-chain — ladder squaring
static __device__ __forceinline__ void cmm32_pp(
    const unsigned* __restrict__ Aprl, const unsigned* __restrict__ ApiI,
    const unsigned* __restrict__ Bprl, const unsigned* __restrict__ BpiI,
    int arow, int bcol, int khalf,
    float16_t& R, float16_t& I)
{
#pragma unroll
    for (int ks = 0; ks < 4; ++ks) {
        const int k0 = ks*16 + khalf;
        short8 Arh, Arl, Aih, Ail, Brh, Brl, Bih, Bil;
        frag_packed(Aprl + arow*RSW + k0, Arh, Arl);
        frag_packed(ApiI + arow*RSW + k0, Aih, Ail);
        frag_packed(Bprl + bcol*RSW + k0, Brh, Brl);
        frag_packed(BpiI + bcol*RSW + k0, Bih, Bil);
        short8 nAih = neg8(Aih), nAil = neg8(Ail);
        R = MFMA32(Arh, Brh, R);  I = MFMA32(Arh, Bih, I);
        R = MFMA32(Arh, Brl, R);  I = MFMA32(Arh, Bil, I);
        R = MFMA32(Arl, Brh, R);  I = MFMA32(Arl, Bih, I);
        R = MFMA32(nAih, Bih, R); I = MFMA32(Aih, Brh, I);
        R = MFMA32(nAih, Bil, R); I = MFMA32(Ail, Brh, I);
        R = MFMA32(nAil, Bih, R); I = MFMA32(Aih, Brl, I);
    }
}

// packed XT store: 4 consecutive rows at one col -> one uint4 per plane
static __device__ __forceinline__ void store_XTp(
    unsigned* XTrl, unsigned* XTiI, int rowbase, int col,
    const float* p_r, const float* p_i)
{
    uint4 w;
    w.x = pack2(p_r[0]); w.y = pack2(p_r[1]); w.z = pack2(p_r[2]); w.w = pack2(p_r[3]);
    *(uint4*)&XTrl[col*RSW + rowbase] = w;
    w.x = pack2(p_i[0]); w.y = pack2(p_i[1]); w.z = pack2(p_i[2]); w.w = pack2(p_i[3]);
    *(uint4*)&XTiI[col*RSW + rowbase] = w;
}

// k[h, 64j+i] = Re( g_j . x_i ),  g_j = c^T (dA^64)^j,  x_i = dA^i dB
// Cubic Newton: X1 = I + (dt/2)A; Y = Ab*X1; V = X1*Y; X2 = 3X1 - 3V + VY.
// P = dA = 2*X2 - I folded into m3 epilogue.
// dB = dt/2 (dA b + b): u = dA*b, then x0 = dt/2(u+b), x1 = dt/2(dA u + u).
// m1/m2/m3 on waves 0-7 (paired 16x32 tiles — round-11 post-mortem: 16-wave
// single tiles regressed; pairing's A-reuse wins in this latency regime).
// Ladder: 9 squarings on waves 0-3 (32x32, 2-chain, setprio); riders
// concurrent on waves 8-15. ALL matrices pair-packed u32 ([hi|lo] per value);
// XT double-buffered with pre-barrier uint4 stores (rounds 10/11 lineage).
// Parity: m3 writes XT0; round s reads XT[(s-1)&1], writes XT[s&1]; tail XT1.
__global__ __launch_bounds__(NTH, 4) void ssm_kernel(
    const float* __restrict__ Ag,
    const float* __restrict__ Bg,
    const float* __restrict__ Cg,
    const float* __restrict__ LogDt,
    float* __restrict__ outp)
{
    __shared__ __align__(16) unsigned char lds[157696];
    unsigned* XRrl  = (unsigned*)(lds);           // packed P rows [rh|rl] (17408 B)
    unsigned* XRiI  = (unsigned*)(lds + 17408);   // packed P rows [ih|il]
    unsigned* XT0rl = (unsigned*)(lds + 34816);   // packed P^T buf0
    unsigned* XT0iI = (unsigned*)(lds + 52224);
    unsigned* XT1rl = (unsigned*)(lds + 69632);   // packed P^T buf1
    unsigned* XT1iI = (unsigned*)(lds + 87040);
    unsigned* XFrl  = (unsigned*)(lds + 104448);  // packed Xf rows (Y^T in Newton)
    unsigned* XFiI  = (unsigned*)(lds + 121856);
    unsigned* Gmrl  = (unsigned*)(lds + 139264);  // packed G rows (32 x RSW)
    unsigned* GmiI  = (unsigned*)(lds + 147968);
    float* bvr = (float*)(lds + 156672);
    float* bvi = (float*)(lds + 156928);
    float* urr = (float*)(lds + 157184);   // u = dA*b scratch
    float* uri = (float*)(lds + 157440);

    const int t    = threadIdx.x;
    const int lane = t & 63;
    const int wv   = t >> 6;                 // 0..15
    const int fm   = lane & 15, fq = lane >> 4;
    const int h    = blockIdx.x;

    // paired-tile mapping (waves 0-7): row band tip, col halves tjp*32 + {0,16}
    const int tip  = wv >> 1, tjp = wv & 1;
    const int parow = tip*16 + fm;
    const int pb0   = tjp*32 + fm;

    // 32x32 squaring mapping (waves 0-3): tile (ti2, tj2)
    const int ti2 = (wv >> 1) & 1, tj2 = wv & 1;
    const int arow32 = ti2*32 + (lane & 31);
    const int bcol32 = tj2*32 + (lane & 31);
    const int khalf  = (lane >> 5) * 8;

    const float dt  = expf(LogDt[h]);
    const float hdt = 0.5f * dt;

    const float2* A2 = (const float2*)(Ag + (size_t)h * NN * NN * 2);
    const float4_t z4 = {0.f, 0.f, 0.f, 0.f};

    // ---- seed P = X1 = I + (dt/2)A (XR + XT0, both packed); load b, c ----
#pragma unroll
    for (int e = 0; e < 4; ++e) {
        int idx = t + e*NTH;
        int i = idx >> 6, j = idx & 63;
        float2 a = A2[idx];
        float x1r = (i == j ? 1.0f : 0.0f) + hdt * a.x;
        float x1i = hdt * a.y;
        unsigned wr = pack2(x1r), wi = pack2(x1i);
        XRrl[i*RSW + j] = wr;
        XRiI[i*RSW + j] = wi;
        XT0rl[j*RSW + i] = wr;
        XT0iI[j*RSW + i] = wi;
    }
    if (t < NN) {
        float2 bv = ((const float2*)Bg)[h*NN + t];
        float2 cv = ((const float2*)Cg)[h*NN + t];
        bvr[t] = bv.x; bvi[t] = bv.y;
        Gmrl[t] = pack2(cv.x);                // g_0 = c (row 0)
        GmiI[t] = pack2(cv.y);
    }
    __syncthreads();

    // ---- m1: Y = Ab*X1 (Ab from global, Bt = XT0); paired; Y^T -> XF (uint2) ----
    if (wv < 8) {
        float4_t P0 = z4, N0 = z4, I10 = z4, I20 = z4;
        float4_t P1 = z4, N1 = z4, I11 = z4, I21 = z4;
#pragma unroll
        for (int ks = 0; ks < 2; ++ks) {
            const int k0 = ks*32 + fq*8;
            unsigned vr[8], vi[8];
#pragma unroll
            for (int j = 0; j < 8; ++j) {
                float2 a = A2[parow*NN + k0 + j];
                vr[j] = __float_as_uint((parow == k0 + j ? 1.0f : 0.0f) - hdt * a.x);
                vi[j] = __float_as_uint(-hdt * a.y);
            }
            short8 Arh, Arl, Aih, Ail;
            frag_vals(vr, Arh, Arl);
            frag_vals(vi, Aih, Ail);
#pragma unroll
            for (int p = 0; p < 2; ++p) {
                short8 Brh, Brl, Bih, Bil;
                frag_packed(XT0rl + (pb0 + p*16)*RSW + k0, Brh, Brl);
                frag_packed(XT0iI + (pb0 + p*16)*RSW + k0, Bih, Bil);
                float4_t &aP = p ? P1 : P0, &aN = p ? N1 : N0;
                float4_t &aI1 = p ? I11 : I10, &aI2 = p ? I21 : I20;
                aP = MFMA(Arh, Brh, aP); aP = MFMA(Arh, Brl, aP); aP = MFMA(Arl, Brh, aP);
                aN = MFMA(Aih, Bih, aN); aN = MFMA(Aih, Bil, aN); aN = MFMA(Ail, Bih, aN);
                aI1 = MFMA(Arh, Bih, aI1); aI1 = MFMA(Arh, Bil, aI1); aI1 = MFMA(Arl, Bih, aI1);
                aI2 = MFMA(Aih, Brh, aI2); aI2 = MFMA(Aih, Brl, aI2); aI2 = MFMA(Ail, Brh, aI2);
            }
        }
#pragma unroll
        for (int p = 0; p < 2; ++p) {
            const int bcol = pb0 + p*16;
            const float4_t &aP = p ? P1 : P0, &aN = p ? N1 : N0;
            const float4_t &aI1 = p ? I11 : I10, &aI2 = p ? I21 : I20;
#pragma unroll
            for (int rp = 0; rp < 2; ++rp) {   // Y^T contiguous rows -> packed uint2
                int row0 = tip*16 + fq*4 + rp*2;
                uint2 w;
                w.x = pack2(aP[rp*2]   - aN[rp*2]);
                w.y = pack2(aP[rp*2+1] - aN[rp*2+1]);
                *(uint2*)&XFrl[bcol*RSW + row0] = w;
                w.x = pack2(aI1[rp*2]   + aI2[rp*2]);
                w.y = pack2(aI1[rp*2+1] + aI2[rp*2+1]);
                *(uint2*)&XFiI[bcol*RSW + row0] = w;
            }
        }
    }
    __syncthreads();

    // ---- m2: V = X1*Y (A = XR packed, Bt = U = XF packed); paired; V -> XR ----
    {
        float4_t P0 = z4, N0 = z4, I10 = z4, I20 = z4;
        float4_t P1 = z4, N1 = z4, I11 = z4, I21 = z4;
        if (wv < 8)
            cmm_pair_pp(XRrl, XRiI, XFrl, XFiI, parow, pb0, fq, P0, N0, I10, I20, P1, N1, I11, I21);
        __syncthreads();   // all X1/Y reads done
        if (wv < 8) {
#pragma unroll
            for (int p = 0; p < 2; ++p) {
                const int bcol = pb0 + p*16;
#pragma unroll
                for (int r = 0; r < 4; ++r) {
                    int row = tip*16 + fq*4 + r;
                    float vr = (p ? P1[r] : P0[r]) - (p ? N1[r] : N0[r]);
                    float vi = (p ? I11[r] : I10[r]) + (p ? I21[r] : I20[r]);
                    XRrl[row*RSW + bcol] = pack2(vr);
                    XRiI[row*RSW + bcol] = pack2(vi);
                }
            }
        }
    }
    __syncthreads();

    // ---- m3: P = dA = 2*(3X1 - 3V + V*Y) - I ; XT0 store pre-barrier ----
    {
        float p_r[2][4], p_i[2][4];
        if (wv < 8) {
            float4_t P0 = z4, N0 = z4, I10 = z4, I20 = z4;
            float4_t P1 = z4, N1 = z4, I11 = z4, I21 = z4;
            cmm_pair_pp(XRrl, XRiI, XFrl, XFiI, parow, pb0, fq, P0, N0, I10, I20, P1, N1, I11, I21);
#pragma unroll
            for (int p = 0; p < 2; ++p) {
                const int bcol = pb0 + p*16;
                const float4_t &aP = p ? P1 : P0, &aN = p ? N1 : N0;
                const float4_t &aI1 = p ? I11 : I10, &aI2 = p ? I21 : I20;
#pragma unroll
                for (int r = 0; r < 4; ++r) {      // pre-barrier elementwise reads
                    int row = tip*16 + fq*4 + r;
                    float2 a = A2[row*NN + bcol];
                    float dd  = (row == bcol ? 1.0f : 0.0f);
                    float x1r = dd + hdt * a.x;
                    float x1i = hdt * a.y;
                    float vvr = unpack2(XRrl[row*RSW + bcol]);
                    float vvi = unpack2(XRiI[row*RSW + bcol]);
                    p_r[p][r] = 2.0f*(3.0f*x1r - 3.0f*vvr + (aP[r] - aN[r])) - dd;
                    p_i[p][r] = 2.0f*(3.0f*x1i - 3.0f*vvi + (aI1[r] + aI2[r]));
                }
                // XT0 has no reader during m3 -> store pre-barrier (uint4)
                store_XTp(XT0rl, XT0iI, tip*16 + fq*4, bcol, p_r[p], p_i[p]);
            }
        }
        __syncthreads();   // all V/Y reads done
        if (wv < 8) {
#pragma unroll
            for (int p = 0; p < 2; ++p) {
                const int bcol = pb0 + p*16;
#pragma unroll
                for (int r = 0; r < 4; ++r) {
                    int row = tip*16 + fq*4 + r;
                    XRrl[row*RSW + bcol] = pack2(p_r[p][r]);
                    XRiI[row*RSW + bcol] = pack2(p_i[p][r]);
                }
            }
        }
    }
    __syncthreads();
    // P = dA (XR packed + XT0 packed)

    // ---- u = dA*b (all 16 waves; lane owns 4 consecutive k -> uint4 reads) ----
    {
        int n = t >> 4, part = t & 15;
        uint4 Wr = *(const uint4*)(XRrl + n*RSW + part*4);
        uint4 Wi = *(const uint4*)(XRiI + n*RSW + part*4);
        unsigned wr[4] = {Wr.x, Wr.y, Wr.z, Wr.w};
        unsigned wi[4] = {Wi.x, Wi.y, Wi.z, Wi.w};
        float ar = 0.f, ai = 0.f;
#pragma unroll
        for (int e = 0; e < 4; ++e) {
            float mr = unpack2(wr[e]);
            float mi = unpack2(wi[e]);
            int k = part*4 + e;
            ar += mr*bvr[k] - mi*bvi[k];
            ai += mr*bvi[k] + mi*bvr[k];
        }
#pragma unroll
        for (int off = 8; off; off >>= 1) { ar += __shfl_xor(ar, off); ai += __shfl_xor(ai, off); }
        if (part == 0) { urr[n] = ar; uri[n] = ai; }
    }
    __syncthreads();

    // ---- ladder s = 1..9: riders (waves 8-15) CONCURRENT with 32x32 squaring (waves 0-3) ----
#pragma unroll 1
    for (int s = 1; s <= 9; ++s) {
        unsigned* XTcrl = (s & 1) ? XT0rl : XT1rl;   // written by previous round
        unsigned* XTciI = (s & 1) ? XT0iI : XT1iI;
        unsigned* XTnrl = (s & 1) ? XT1rl : XT0rl;   // no reader this round
        unsigned* XTniI = (s & 1) ? XT1iI : XT0iI;
        float16_t sR, sI;
        if (wv >= 8) {
            if (s == 1) {
                // x0 = h(u+b); x1 = h(dA u + u): 512 threads; lane owns 8 consecutive k
                int n = (t >> 3) & 63, part = t & 7;
                const unsigned* rp0 = XRrl + n*RSW + part*8;
                const unsigned* ip0 = XRiI + n*RSW + part*8;
                uint4 Wr0 = *(const uint4*)(rp0), Wr1 = *(const uint4*)(rp0 + 4);
                uint4 Wi0 = *(const uint4*)(ip0), Wi1 = *(const uint4*)(ip0 + 4);
                unsigned wr[8] = {Wr0.x, Wr0.y, Wr0.z, Wr0.w, Wr1.x, Wr1.y, Wr1.z, Wr1.w};
                unsigned wi[8] = {Wi0.x, Wi0.y, Wi0.z, Wi0.w, Wi1.x, Wi1.y, Wi1.z, Wi1.w};
                float ar = 0.f, ai = 0.f;
#pragma unroll
                for (int e = 0; e < 8; ++e) {
                    float mr = unpack2(wr[e]);
                    float mi = unpack2(wi[e]);
                    int k = part*8 + e;
                    ar += mr*urr[k] - mi*uri[k];
                    ai += mr*uri[k] + mi*urr[k];
                }
#pragma unroll
                for (int off = 4; off; off >>= 1) { ar += __shfl_xor(ar, off); ai += __shfl_xor(ai, off); }
                if (part == 0) {
                    float u_r = urr[n], u_i = uri[n];
                    XFrl[n]       = pack2(hdt*(u_r + bvr[n]));
                    XFiI[n]       = pack2(hdt*(u_i + bvi[n]));
                    XFrl[RSW + n] = pack2(hdt*(ar + u_r));
                    XFiI[RSW + n] = pack2(hdt*(ai + u_i));
                }
            } else if (s <= 6) {
                const int C = 1 << (s-1);
                const int w = wv - 8;
                const int nT = (s == 6) ? 8 : 4;
                if (w < nT) {
                    const int rt = w >> 2, ct = w & 3;
                    float4_t aP = z4, aN = z4, aI1 = z4, aI2 = z4;
                    cmm_pp<true>(XFrl, XFiI, XRrl, XRiI, rt*16 + fm, ct*16 + fm, fq, aP, aN, aI1, aI2);
#pragma unroll
                    for (int r = 0; r < 4; ++r) {
                        int orow = C + rt*16 + fq*4 + r;
                        int oc   = ct*16 + fm;
                        XFrl[orow*RSW + oc] = pack2(aP[r] - aN[r]);
                        XFiI[orow*RSW + oc] = pack2(aI1[r] + aI2[r]);
                    }
                }
            } else {
                const int C = 1 << (s-7);     // 1,2,4
                const int w = wv - 8;
                if (w < 4) {
                    float4_t aP = z4, aN = z4, aI1 = z4, aI2 = z4;
                    cmm_pp<true>(Gmrl, GmiI, XTcrl, XTciI, fm, w*16 + fm, fq, aP, aN, aI1, aI2);
#pragma unroll
                    for (int r = 0; r < 4; ++r) {
                        int orow = C + fq*4 + r;   // <= 19 < 32, no mask
                        int oc   = w*16 + fm;
                        Gmrl[orow*RSW + oc] = pack2(aP[r] - aN[r]);
                        GmiI[orow*RSW + oc] = pack2(aI1[r] + aI2[r]);
                    }
                }
            }
        } else if (wv < 4) {
            // squaring (waves 0-3, 32x32 tiles, 2-chain): P <- P*P
#pragma unroll
            for (int g = 0; g < 16; ++g) { sR[g] = 0.f; sI[g] = 0.f; }
            __builtin_amdgcn_s_setprio(1);   // T5: favor the long-pole MFMA waves
            cmm32_pp(XRrl, XRiI, XTcrl, XTciI, arow32, bcol32, khalf, sR, sI);
            __builtin_amdgcn_s_setprio(0);
            // pre-barrier: XT_next stores (no reader this round), uint4 packed
            {
                const int col = tj2*32 + (lane & 31);
                const int hi4 = (lane >> 5) * 4;
#pragma unroll
                for (int q = 0; q < 4; ++q) {
                    float r4[4], i4[4];
#pragma unroll
                    for (int rr = 0; rr < 4; ++rr) { r4[rr] = sR[4*q+rr]; i4[rr] = sI[4*q+rr]; }
                    store_XTp(XTnrl, XTniI, ti2*32 + 8*q + hi4, col, r4, i4);
                }
            }
        }
        __syncthreads();   // all XR reads (riders + frags) complete
        if (wv < 4 && s < 9) {
            // XR b32 packed stores (dead at s=9 -> skipped)
            const int col = tj2*32 + (lane & 31);
            const int hi4 = (lane >> 5) * 4;
#pragma unroll
            for (int q = 0; q < 4; ++q) {
                const int rowb = ti2*32 + 8*q + hi4;
#pragma unroll
                for (int rr = 0; rr < 4; ++rr) {
                    XRrl[(rowb + rr)*RSW + col] = pack2(sR[4*q+rr]);
                    XRiI[(rowb + rr)*RSW + col] = pack2(sI[4*q+rr]);
                }
            }
        }
        __syncthreads();
    }
    // P = dA^512 (XT1 packed) ; XF rows 0..63 = x_i ; Gm rows 0..7 = g_0..g_7

    // ---- tail tt = 0..3: chained dA^512 G-steps + K tiles (direct global) ----
    // G rows [8+8tt, 24+8tt) <- A rows [8tt, 8tt+16) (out row 8+ab+m depends
    // only on A row ab+m, so in-interval row overlap is benign).
#pragma unroll 1
    for (int tt = 0; tt < 4; ++tt) {
        if (tt < 3 && wv < 4) {
            const int ab = tt * 8;
            float4_t aP = z4, aN = z4, aI1 = z4, aI2 = z4;
            cmm_pp<true>(Gmrl, GmiI, XT1rl, XT1iI, ab + fm, wv*16 + fm, fq, aP, aN, aI1, aI2);
#pragma unroll
            for (int r = 0; r < 4; ++r) {
                int orow = 8 + ab + fq*4 + r;
                if (orow < 32) {
                    int oc = wv*16 + fm;
                    Gmrl[orow*RSW + oc] = pack2(aP[r] - aN[r]);
                    GmiI[orow*RSW + oc] = pack2(aI1[r] + aI2[r]);
                }
            }
        }
        if (wv >= 4 && wv < 8) {           // K rows [8tt, 8tt+8): direct global store
            const int jb = tt * 8;
            // clamp A row inside Gm's 32 rows (rows >= 32 feed only discarded C rows)
            int ga = jb + fm; if (ga > 31) ga = 31;
            float4_t aP = z4, aN = z4, aI1 = z4, aI2 = z4;
            __builtin_amdgcn_s_setprio(1);
            cmm_pp<false>(Gmrl, GmiI, XFrl, XFiI, ga, (wv-4)*16 + fm, fq, aP, aN, aI1, aI2);
            __builtin_amdgcn_s_setprio(0);
            if (fq < 2) {
                size_t base = (size_t)h * LSEQ;
#pragma unroll
                for (int r = 0; r < 4; ++r)
                    outp[base + (jb + fq*4 + r)*NN + (wv-4)*16 + fm] = aP[r] - aN[r];
            }
        }
        if (tt < 3) __syncthreads();
    }
}

extern "C" void kernel_launch(void* const* d_in, const int* in_sizes, int n_in,
                              void* d_out, int out_size, void* d_ws, size_t ws_size,
                              hipStream_t stream) {
    const float* A  = (const float*)d_in[0];
    const float* B  = (const float*)d_in[1];
    const float* C  = (const float*)d_in[2];
    const float* ld = (const float*)d_in[3];
    float* out = (float*)d_out;
    ssm_kernel<<<dim3(NH), dim3(NTH), 0, stream>>>(A, B, C, ld, out);
}